// Round 19
// baseline (113.335 us; speedup 1.0000x reference)
//
#include <hip/hip_runtime.h>
#include <math.h>

#define N_NODES 20000
#define IN_DIM  512
#define HID     128
#define HEADS   8
#define C_DIM   16
#define LAYERS  2
#define NEDGE   320000
#define NEG_SLOPE 0.2f
#define LN_EPS  1e-5f
#define CAP     64   // ELL capacity (incl. self loop); deg ~ Poisson(16)

#define PROJ_BLKS  313                         // ceil(20000/64), 64 rows per 256-thr block
#define EDGE_BLKS  ((NEDGE + 255) / 256)       // 1250
#define SELF_BLKS  ((N_NODES + 255) / 256)     // 79
#define GEMM_BLKS  313                         // ceil(20000/64) for k_xlxr

typedef __attribute__((ext_vector_type(8))) short short8;
typedef __attribute__((ext_vector_type(4))) float f32x4;
typedef __attribute__((ext_vector_type(2))) float f32x2;

__device__ __forceinline__ unsigned short f2bf(float f) {
    unsigned int u = __float_as_uint(f);
    u += 0x7fffu + ((u >> 16) & 1u);
    return (unsigned short)(u >> 16);
}
__device__ __forceinline__ float bf2f(unsigned short s) {
    return __uint_as_float(((unsigned int)s) << 16);
}

// ------- one-time: cnt=0; weights -> bf16 transposed [n][k] (coalesced reads) -------
__global__ __launch_bounds__(256) void k_convert(
    const float* __restrict__ W_in, const float* __restrict__ Wl, const float* __restrict__ Wr,
    unsigned short* __restrict__ WtI, unsigned short* __restrict__ Wlt, unsigned short* __restrict__ Wrt,
    int* __restrict__ cnt)
{
    int i = blockIdx.x * 256 + threadIdx.x;
    if (i < N_NODES) cnt[i] = 0;
    if (i < 65536) {                      // read W_in[k][n] coalesced, write WtI[n][k]
        int n = i & 127, k = i >> 7;
        WtI[(unsigned)n * IN_DIM + k] = f2bf(W_in[(unsigned)k * HID + n]);
    } else if (i < 98304) {               // Wlt[L][n][k]
        int r = i - 65536;
        int L = r >> 14, q = r & 16383;
        int n = q & 127, k = q >> 7;
        Wlt[L * 16384 + n * HID + k] = f2bf(Wl[L * 16384 + k * HID + n]);
    } else if (i < 131072) {              // Wrt[L][n][k]
        int r = i - 98304;
        int L = r >> 14, q = r & 16383;
        int n = q & 127, k = q >> 7;
        Wrt[L * 16384 + n * HID + k] = f2bf(Wr[L * 16384 + k * HID + n]);
    }
}

// ------- fused: input proj (blocks [0,313)) + edge build + self-loop insert -------
__global__ __launch_bounds__(256) void k_fused0(
    const float* __restrict__ x, const unsigned short* __restrict__ WtI,
    const float* __restrict__ b, const float* __restrict__ g, const float* __restrict__ beta,
    unsigned short* __restrict__ hb,
    const int* __restrict__ ei, int* __restrict__ cnt, int* __restrict__ adj)
{
    __shared__ unsigned short wlds[128][136];   // [n][k-chunk]
    const int bid = blockIdx.x;
    const int tid = threadIdx.x;

    if (bid >= PROJ_BLKS) {
        if (bid < PROJ_BLKS + EDGE_BLKS) {
            int e = (bid - PROJ_BLKS) * 256 + tid;
            if (e < NEDGE) {
                int src = ei[e];
                int dst = ei[NEDGE + e];
                int r = atomicAdd(&cnt[dst], 1);
                if (r < CAP) adj[(unsigned)dst * CAP + r] = src;
            }
        } else {
            int i = (bid - PROJ_BLKS - EDGE_BLKS) * 256 + tid;
            if (i < N_NODES) {
                int r = atomicAdd(&cnt[i], 1);
                if (r < CAP) adj[(unsigned)i * CAP + r] = i;
            }
        }
        return;
    }

    const int wid = tid >> 6;
    const int l   = tid & 63;
    const int grp = l >> 4;
    const int ln  = l & 15;
    const int row0 = bid * 64 + wid * 16;            // wave's 16-row group
    const int arow = min(row0 + ln, N_NODES - 1);    // clamp for tail block

    // preload all 16 A-fragments from f32 x directly (32B contiguous per lane)
    short8 a[16];
#pragma unroll
    for (int ks = 0; ks < 16; ++ks) {
        const float4* px = (const float4*)&x[(unsigned)arow * IN_DIM + ks * 32 + grp * 8];
        float4 xa = px[0], xb4 = px[1];
        short8 o;
        o[0] = (short)f2bf(xa.x); o[1] = (short)f2bf(xa.y);
        o[2] = (short)f2bf(xa.z); o[3] = (short)f2bf(xa.w);
        o[4] = (short)f2bf(xb4.x); o[5] = (short)f2bf(xb4.y);
        o[6] = (short)f2bf(xb4.z); o[7] = (short)f2bf(xb4.w);
        a[ks] = o;
    }

    f32x4 acc[8];
#pragma unroll
    for (int j = 0; j < 8; ++j) acc[j] = (f32x4){0.f, 0.f, 0.f, 0.f};

    const int sr = tid >> 4;           // 0..15
    const int sc = (tid & 15) * 8;

    for (int kc = 0; kc < 4; ++kc) {
        __syncthreads();
#pragma unroll
        for (int rr = sr; rr < 128; rr += 16)
            *(short8*)&wlds[rr][sc] = *(const short8*)&WtI[rr * IN_DIM + kc * 128 + sc];
        __syncthreads();
#pragma unroll
        for (int ks = 0; ks < 4; ++ks) {
#pragma unroll
            for (int j = 0; j < 8; ++j) {
                short8 bf = *(short8*)&wlds[j * 16 + ln][ks * 32 + grp * 8];
                acc[j] = __builtin_amdgcn_mfma_f32_16x16x32_bf16(a[kc * 4 + ks], bf, acc[j], 0, 0, 0);
            }
        }
    }
    // epilogue: +bias, LN over 128 cols (intra-wave, 16-lane groups), ReLU
    float s1[4] = {0, 0, 0, 0}, s2[4] = {0, 0, 0, 0};
#pragma unroll
    for (int j = 0; j < 8; ++j) {
        float bb = b[j * 16 + ln];
#pragma unroll
        for (int r = 0; r < 4; ++r) {
            float v = acc[j][r] + bb;
            acc[j][r] = v;
            s1[r] += v; s2[r] += v * v;
        }
    }
#pragma unroll
    for (int r = 0; r < 4; ++r) {
#pragma unroll
        for (int off = 8; off; off >>= 1) {
            s1[r] += __shfl_xor(s1[r], off);
            s2[r] += __shfl_xor(s2[r], off);
        }
    }
#pragma unroll
    for (int r = 0; r < 4; ++r) {
        float mu  = s1[r] * (1.f / HID);
        float var = s2[r] * (1.f / HID) - mu * mu;
        float rs  = rsqrtf(var + LN_EPS);
        int row = row0 + grp * 4 + r;
        if (row < N_NODES) {
#pragma unroll
            for (int j = 0; j < 8; ++j) {
                int c = j * 16 + ln;
                float o = (acc[j][r] - mu) * rs * g[c] + beta[c];
                hb[(unsigned)row * HID + c] = f2bf(fmaxf(o, 0.f));
            }
        }
    }
}

// ------- per-layer MFMA: 64-row tile, 256 thr = 4 waves; LDS-staged weights -------
__global__ __launch_bounds__(256) void k_xlxr(
    const unsigned short* __restrict__ hb,
    const unsigned short* __restrict__ Wlt, const unsigned short* __restrict__ Wrt,
    const float* __restrict__ bl, const float* __restrict__ br,
    unsigned short* __restrict__ xlb, unsigned short* __restrict__ xrb)
{
    __shared__ unsigned short wl_lds[128][136];
    __shared__ unsigned short wr_lds[128][136];
    const int tid = threadIdx.x;
    const int wid = tid >> 6;
    const int l   = tid & 63;
    const int grp = l >> 4;
    const int ln  = l & 15;
    const int row0 = blockIdx.x * 64 + wid * 16;
    const int arow = min(row0 + ln, N_NODES - 1);    // clamp for tail block

    const int sr = tid >> 4;           // 0..15
    const int sc = (tid & 15) * 8;
#pragma unroll
    for (int rr = sr; rr < 128; rr += 16) {
        *(short8*)&wl_lds[rr][sc] = *(const short8*)&Wlt[rr * HID + sc];
        *(short8*)&wr_lds[rr][sc] = *(const short8*)&Wrt[rr * HID + sc];
    }

    short8 a[4];
#pragma unroll
    for (int ks = 0; ks < 4; ++ks)
        a[ks] = *(const short8*)&hb[(unsigned)arow * HID + ks * 32 + grp * 8];
    __syncthreads();

    f32x4 aL[8], aR[8];
#pragma unroll
    for (int j = 0; j < 8; ++j) {
        aL[j] = (f32x4){0.f, 0.f, 0.f, 0.f};
        aR[j] = (f32x4){0.f, 0.f, 0.f, 0.f};
    }
#pragma unroll
    for (int ks = 0; ks < 4; ++ks) {
        const int kk = ks * 32 + grp * 8;
#pragma unroll
        for (int j = 0; j < 8; ++j) {
            short8 b8l = *(short8*)&wl_lds[j * 16 + ln][kk];
            aL[j] = __builtin_amdgcn_mfma_f32_16x16x32_bf16(a[ks], b8l, aL[j], 0, 0, 0);
            short8 b8r = *(short8*)&wr_lds[j * 16 + ln][kk];
            aR[j] = __builtin_amdgcn_mfma_f32_16x16x32_bf16(a[ks], b8r, aR[j], 0, 0, 0);
        }
    }
#pragma unroll
    for (int r = 0; r < 4; ++r) {
        int row = row0 + grp * 4 + r;
        if (row < N_NODES) {
#pragma unroll
            for (int j = 0; j < 8; ++j) {
                int c = j * 16 + ln;
                xlb[(unsigned)row * HID + c] = f2bf(aL[j][r] + bl[c]);
                xrb[(unsigned)row * HID + c] = f2bf(aR[j][r] + br[c]);
            }
        }
    }
}

// per-slot work, float2-paired, parameterized per node
#define PROC2(xa, xb_, live, rvv, accv, spv) do {                           \
    f32x2 xf2[8];                                                           \
    _Pragma("unroll")                                                       \
    for (int q = 0; q < 4; ++q) {                                           \
        unsigned w0 = ((const unsigned*)&(xa))[q];                          \
        f32x2 v0;                                                           \
        v0.x = __uint_as_float(w0 << 16);                                   \
        v0.y = __uint_as_float(w0 & 0xffff0000u);                           \
        xf2[q] = v0;                                                        \
        unsigned w1 = ((const unsigned*)&(xb_))[q];                         \
        f32x2 v1;                                                           \
        v1.x = __uint_as_float(w1 << 16);                                   \
        v1.y = __uint_as_float(w1 & 0xffff0000u);                           \
        xf2[4 + q] = v1;                                                    \
    }                                                                       \
    f32x2 ll2 = {0.f, 0.f};                                                 \
    _Pragma("unroll")                                                       \
    for (int q = 0; q < 8; ++q) {                                           \
        f32x2 u = xf2[q] + rvv[q];                                          \
        f32x2 un = u * nsl2;                                                \
        u.x = fmaxf(u.x, un.x);                                             \
        u.y = fmaxf(u.y, un.y);                                             \
        ll2 = u * av2[q] + ll2;                                             \
    }                                                                       \
    float p = (live) ? __expf(ll2.x + ll2.y) : 0.f;                         \
    spv += p;                                                               \
    f32x2 p2 = {p, p};                                                      \
    _Pragma("unroll")                                                       \
    for (int q = 0; q < 8; ++q) accv[q] = p2 * xf2[q] + accv[q];            \
} while (0)

#define UNPACK8(pr, dst) do {                                               \
    short8 r0_ = (pr)[0], r1_ = (pr)[1];                                    \
    _Pragma("unroll")                                                       \
    for (int q = 0; q < 4; ++q) {                                           \
        unsigned w0 = ((const unsigned*)&r0_)[q];                           \
        f32x2 v0;                                                           \
        v0.x = __uint_as_float(w0 << 16);                                   \
        v0.y = __uint_as_float(w0 & 0xffff0000u);                           \
        dst[q] = v0;                                                        \
        unsigned w1 = ((const unsigned*)&r1_)[q];                           \
        f32x2 v1;                                                           \
        v1.x = __uint_as_float(w1 << 16);                                   \
        v1.y = __uint_as_float(w1 & 0xffff0000u);                           \
        dst[4 + q] = v1;                                                    \
    }                                                                       \
} while (0)

// ------- fused GAT layer: TWO NODES PER WAVE (ILP), zero barriers, packed-f32 -------
__global__ __launch_bounds__(256) void k_gat(
    const unsigned short* __restrict__ xlb, const unsigned short* __restrict__ xrb,
    const int* __restrict__ adj, const int* __restrict__ cnt,
    const float* __restrict__ att, const float* __restrict__ gbias,
    const float* __restrict__ g, const float* __restrict__ beta,
    const unsigned short* __restrict__ hbin, float* __restrict__ hout,
    unsigned short* __restrict__ hbout)
{
    __shared__ float red[4][2][136];     // per-wave, per-node: [0..127] acc, [128..135] sums
    const int tid  = threadIdx.x;
    const int wv   = tid >> 6;
    const int lane = tid & 63;
    const int dA   = blockIdx.x * 8 + wv * 2;
    const int dB   = dA + 1;
    const int e    = lane >> 3;
    const int hh   = lane & 7;
    const int cb   = hh * 16;
    const unsigned dCA = (unsigned)dA * CAP;
    const unsigned dCB = (unsigned)dB * CAP;

    const int njA = min(cnt[dA], CAP);
    const int njB = min(cnt[dB], CAP);
    const int njM = max(njA, njB);

    // all adjacency loads issued up front (6 independent)
    int ajA0 = adj[dCA + e], ajA1 = adj[dCA + 8 + e], ajA2 = adj[dCA + 16 + e];
    int ajB0 = adj[dCB + e], ajB1 = adj[dCB + 8 + e], ajB2 = adj[dCB + 16 + e];

    const f32x2 nsl2 = {NEG_SLOPE, NEG_SLOPE};
    f32x2 av2[8], rvA[8], rvB[8];
#pragma unroll
    for (int q = 0; q < 8; ++q)
        av2[q] = *(const f32x2*)&att[cb + q * 2];
    UNPACK8((const short8*)&xrb[(unsigned)dA * HID + cb], rvA);
    UNPACK8((const short8*)&xrb[(unsigned)dB * HID + cb], rvB);

    // chunk 0/1 gathers for both nodes, issued before any compute
    const int sA0 = (e < njA)     ? ajA0 : dA;
    const int sA1 = (8 + e < njA) ? ajA1 : dA;
    const int sB0 = (e < njB)     ? ajB0 : dB;
    const int sB1 = (8 + e < njB) ? ajB1 : dB;
    const short8* pA0 = (const short8*)&xlb[(unsigned)sA0 * HID + cb];
    short8 gaA0 = pA0[0], gbA0 = pA0[1];
    const short8* pB0 = (const short8*)&xlb[(unsigned)sB0 * HID + cb];
    short8 gaB0 = pB0[0], gbB0 = pB0[1];
    const short8* pA1 = (const short8*)&xlb[(unsigned)sA1 * HID + cb];
    short8 gaA1 = pA1[0], gbA1 = pA1[1];
    const short8* pB1 = (const short8*)&xlb[(unsigned)sB1 * HID + cb];
    short8 gaB1 = pB1[0], gbB1 = pB1[1];

    f32x2 accA[8], accB[8];
#pragma unroll
    for (int q = 0; q < 8; ++q) { accA[q] = (f32x2){0.f, 0.f}; accB[q] = (f32x2){0.f, 0.f}; }
    float spA = 0.f, spB = 0.f;

    if (njM > 16) {
        const int sA2 = (16 + e < njA) ? ajA2 : dA;
        const int sB2 = (16 + e < njB) ? ajB2 : dB;
        const short8* pA2 = (const short8*)&xlb[(unsigned)sA2 * HID + cb];
        short8 gaA2 = pA2[0], gbA2 = pA2[1];
        const short8* pB2 = (const short8*)&xlb[(unsigned)sB2 * HID + cb];
        short8 gaB2 = pB2[0], gbB2 = pB2[1];
        PROC2(gaA0, gbA0, e < njA,      rvA, accA, spA);
        PROC2(gaB0, gbB0, e < njB,      rvB, accB, spB);
        PROC2(gaA1, gbA1, 8 + e < njA,  rvA, accA, spA);
        PROC2(gaB1, gbB1, 8 + e < njB,  rvB, accB, spB);
        PROC2(gaA2, gbA2, 16 + e < njA, rvA, accA, spA);
        PROC2(gaB2, gbB2, 16 + e < njB, rvB, accB, spB);
        for (int ch = 3; (ch << 3) < njM; ++ch) {   // rare tail
            int j = (ch << 3) + e;
            int sjA = (j < njA) ? adj[dCA + j] : dA;
            int sjB = (j < njB) ? adj[dCB + j] : dB;
            const short8* pjA = (const short8*)&xlb[(unsigned)sjA * HID + cb];
            short8 gajA = pjA[0], gbjA = pjA[1];
            const short8* pjB = (const short8*)&xlb[(unsigned)sjB * HID + cb];
            short8 gajB = pjB[0], gbjB = pjB[1];
            PROC2(gajA, gbjA, j < njA, rvA, accA, spA);
            PROC2(gajB, gbjB, j < njB, rvB, accB, spB);
        }
    } else {
        PROC2(gaA0, gbA0, e < njA,     rvA, accA, spA);
        PROC2(gaB0, gbB0, e < njB,     rvB, accB, spB);
        PROC2(gaA1, gbA1, 8 + e < njA, rvA, accA, spA);
        PROC2(gaB1, gbB1, 8 + e < njB, rvB, accB, spB);
    }

    // butterfly reduce across the 8 slot-lanes (e-bits are lane bits 3..5), both nodes
#pragma unroll
    for (int m = 8; m < 64; m <<= 1) {
#pragma unroll
        for (int q = 0; q < 8; ++q) {
            accA[q].x += __shfl_xor(accA[q].x, m);
            accA[q].y += __shfl_xor(accA[q].y, m);
            accB[q].x += __shfl_xor(accB[q].x, m);
            accB[q].y += __shfl_xor(accB[q].y, m);
        }
        spA += __shfl_xor(spA, m);
        spB += __shfl_xor(spB, m);
    }

    // wave-private LDS redistribute (no barrier: same-wave LDS dependency)
    if (lane < 8) {                      // lane == hh, e == 0
#pragma unroll
        for (int i = 0; i < 4; ++i) {
            float4 vA;
            vA.x = accA[2 * i].x;     vA.y = accA[2 * i].y;
            vA.z = accA[2 * i + 1].x; vA.w = accA[2 * i + 1].y;
            *(float4*)&red[wv][0][lane * 16 + i * 4] = vA;
            float4 vB;
            vB.x = accB[2 * i].x;     vB.y = accB[2 * i].y;
            vB.z = accB[2 * i + 1].x; vB.w = accB[2 * i + 1].y;
            *(float4*)&red[wv][1][lane * 16 + i * 4] = vB;
        }
        red[wv][0][128 + lane] = spA;
        red[wv][1][128 + lane] = spB;
    }
    const int c0 = lane * 2;
    float2 gbv = *(const float2*)&gbias[c0];
    float2 ggv = *(const float2*)&g[c0];
    float2 bev = *(const float2*)&beta[c0];

#pragma unroll
    for (int nn = 0; nn < 2; ++nn) {
        const int d = dA + nn;
        float a0  = red[wv][nn][c0];
        float a1  = red[wv][nn][c0 + 1];
        float ssv = red[wv][nn][128 + e];    // head of channel c0 is c0>>4 == e

        unsigned hr2 = *(const unsigned*)&hbin[(unsigned)d * HID + c0];
        float o0 = a0 / ssv + gbv.x;
        float o1 = a1 / ssv + gbv.y;
        o0 = o0 > 0.f ? o0 : (__expf(o0) - 1.f);   // ELU(alpha=1)
        o1 = o1 > 0.f ? o1 : (__expf(o1) - 1.f);
        o0 += bf2f((unsigned short)(hr2 & 0xffffu));
        o1 += bf2f((unsigned short)(hr2 >> 16));

        float s1l = o0 + o1, s2l = o0 * o0 + o1 * o1;
#pragma unroll
        for (int m = 1; m < 64; m <<= 1) {
            s1l += __shfl_xor(s1l, m);
            s2l += __shfl_xor(s2l, m);
        }
        float mu  = s1l * (1.f / HID);
        float var = s2l * (1.f / HID) - mu * mu;
        float rs  = rsqrtf(var + LN_EPS);
        float out0 = (o0 - mu) * rs * ggv.x + bev.x;
        float out1 = (o1 - mu) * rs * ggv.y + bev.y;
        if (hout) {
            float2 ov; ov.x = out0; ov.y = out1;
            *(float2*)&hout[(unsigned)d * HID + c0] = ov;
        }
        if (hbout) {
            unsigned pk = (unsigned)f2bf(out0) | ((unsigned)f2bf(out1) << 16);
            *(unsigned*)&hbout[(unsigned)d * HID + c0] = pk;
        }
    }
}

extern "C" void kernel_launch(void* const* d_in, const int* in_sizes, int n_in,
                              void* d_out, int out_size, void* d_ws, size_t ws_size,
                              hipStream_t stream) {
    (void)in_sizes; (void)n_in; (void)out_size; (void)ws_size;
    const float* x        = (const float*)d_in[0];
    const int*   ei       = (const int*)  d_in[1];
    const float* W_in     = (const float*)d_in[2];
    const float* b_in     = (const float*)d_in[3];
    const float* ln_g     = (const float*)d_in[4];
    const float* ln_b     = (const float*)d_in[5];
    const float* Wl       = (const float*)d_in[6];
    const float* bl       = (const float*)d_in[7];
    const float* Wr       = (const float*)d_in[8];
    const float* br       = (const float*)d_in[9];
    const float* att      = (const float*)d_in[10];
    const float* gat_bias = (const float*)d_in[11];
    const float* norm_g   = (const float*)d_in[12];
    const float* norm_b   = (const float*)d_in[13];
    float* out_f = (float*)d_out;

    char* w = (char*)d_ws;
    int*   adj = (int*)w;                           w += (size_t)N_NODES * CAP * 4;
    int*   cnt = (int*)w;                           w += (size_t)N_NODES * 4;
    unsigned short* hb  = (unsigned short*)w;       w += (size_t)N_NODES * HID * 2;
    unsigned short* xlb = (unsigned short*)w;       w += (size_t)N_NODES * HID * 2;
    unsigned short* xrb = (unsigned short*)w;       w += (size_t)N_NODES * HID * 2;
    unsigned short* WtI = (unsigned short*)w;       w += (size_t)IN_DIM * HID * 2;
    unsigned short* Wlt = (unsigned short*)w;       w += (size_t)LAYERS * HID * HID * 2;
    unsigned short* Wrt = (unsigned short*)w;

    k_convert<<<512, 256, 0, stream>>>(W_in, Wl, Wr, WtI, Wlt, Wrt, cnt);
    k_fused0<<<PROJ_BLKS + EDGE_BLKS + SELF_BLKS, 256, 0, stream>>>(
        x, WtI, b_in, ln_g, ln_b, hb, ei, cnt, adj);

    for (int L = 0; L < LAYERS; ++L) {
        k_xlxr<<<GEMM_BLKS, 256, 0, stream>>>(
            hb, Wlt + (size_t)L * HID * HID, Wrt + (size_t)L * HID * HID,
            bl + (size_t)L * HID, br + (size_t)L * HID, xlb, xrb);
        float*          hout   = (L == LAYERS - 1) ? out_f : (float*)nullptr;
        unsigned short* hbnext = (L == LAYERS - 1) ? (unsigned short*)nullptr : hb;
        k_gat<<<N_NODES / 8, 256, 0, stream>>>(
            xlb, xrb, adj, cnt,
            att + (size_t)L * HEADS * C_DIM, gat_bias + (size_t)L * HID,
            norm_g + (size_t)L * HID, norm_b + (size_t)L * HID, hb, hout, hbnext);
    }
}

// Round 20
// 100.294 us; speedup vs baseline: 1.1300x; 1.1300x over previous
//
#include <hip/hip_runtime.h>
#include <math.h>

#define N_NODES 20000
#define IN_DIM  512
#define HID     128
#define HEADS   8
#define C_DIM   16
#define LAYERS  2
#define NEDGE   320000
#define NEG_SLOPE 0.2f
#define LN_EPS  1e-5f
#define CAP     64   // ELL capacity (incl. self loop); deg ~ Poisson(16)

#define PROJ_BLKS  313                         // ceil(20000/64), 64 rows per 256-thr block
#define EDGE_BLKS  ((NEDGE + 255) / 256)       // 1250
#define SELF_BLKS  ((N_NODES + 255) / 256)     // 79
#define GEMM_BLKS  313                         // ceil(20000/64) for k_xlxr

typedef __attribute__((ext_vector_type(8))) short short8;
typedef __attribute__((ext_vector_type(4))) float f32x4;
typedef __attribute__((ext_vector_type(2))) float f32x2;

__device__ __forceinline__ unsigned short f2bf(float f) {
    unsigned int u = __float_as_uint(f);
    u += 0x7fffu + ((u >> 16) & 1u);
    return (unsigned short)(u >> 16);
}
__device__ __forceinline__ float bf2f(unsigned short s) {
    return __uint_as_float(((unsigned int)s) << 16);
}

// ------- one-time: cnt=0 (64B-padded); weights -> bf16 transposed [n][k] -------
__global__ __launch_bounds__(256) void k_convert(
    const float* __restrict__ W_in, const float* __restrict__ Wl, const float* __restrict__ Wr,
    unsigned short* __restrict__ WtI, unsigned short* __restrict__ Wlt, unsigned short* __restrict__ Wrt,
    int* __restrict__ cntp)
{
    int i = blockIdx.x * 256 + threadIdx.x;
    if (i < N_NODES) cntp[i << 4] = 0;    // one counter per 64B line
    if (i < 65536) {                      // read W_in[k][n] coalesced, write WtI[n][k]
        int n = i & 127, k = i >> 7;
        WtI[(unsigned)n * IN_DIM + k] = f2bf(W_in[(unsigned)k * HID + n]);
    } else if (i < 98304) {               // Wlt[L][n][k]
        int r = i - 65536;
        int L = r >> 14, q = r & 16383;
        int n = q & 127, k = q >> 7;
        Wlt[L * 16384 + n * HID + k] = f2bf(Wl[L * 16384 + k * HID + n]);
    } else if (i < 131072) {              // Wrt[L][n][k]
        int r = i - 98304;
        int L = r >> 14, q = r & 16383;
        int n = q & 127, k = q >> 7;
        Wrt[L * 16384 + n * HID + k] = f2bf(Wr[L * 16384 + k * HID + n]);
    }
}

// ------- fused: input proj (blocks [0,313)) + edge build + self-loop insert -------
__global__ __launch_bounds__(256) void k_fused0(
    const float* __restrict__ x, const unsigned short* __restrict__ WtI,
    const float* __restrict__ b, const float* __restrict__ g, const float* __restrict__ beta,
    unsigned short* __restrict__ hb,
    const int* __restrict__ ei, int* __restrict__ cntp, int* __restrict__ adj)
{
    __shared__ unsigned short wlds[128][136];   // [n][k-chunk]
    const int bid = blockIdx.x;
    const int tid = threadIdx.x;

    if (bid >= PROJ_BLKS) {
        if (bid < PROJ_BLKS + EDGE_BLKS) {
            int e = (bid - PROJ_BLKS) * 256 + tid;
            if (e < NEDGE) {
                int src = ei[e];
                int dst = ei[NEDGE + e];
                int r = atomicAdd(&cntp[dst << 4], 1);
                if (r < CAP) adj[(unsigned)dst * CAP + r] = src;
            }
        } else {
            int i = (bid - PROJ_BLKS - EDGE_BLKS) * 256 + tid;
            if (i < N_NODES) {
                int r = atomicAdd(&cntp[i << 4], 1);
                if (r < CAP) adj[(unsigned)i * CAP + r] = i;
            }
        }
        return;
    }

    const int wid = tid >> 6;
    const int l   = tid & 63;
    const int grp = l >> 4;
    const int ln  = l & 15;
    const int row0 = bid * 64 + wid * 16;            // wave's 16-row group
    const int arow = min(row0 + ln, N_NODES - 1);    // clamp for tail block

    // preload all 16 A-fragments from f32 x directly (32B contiguous per lane)
    short8 a[16];
#pragma unroll
    for (int ks = 0; ks < 16; ++ks) {
        const float4* px = (const float4*)&x[(unsigned)arow * IN_DIM + ks * 32 + grp * 8];
        float4 xa = px[0], xb4 = px[1];
        short8 o;
        o[0] = (short)f2bf(xa.x); o[1] = (short)f2bf(xa.y);
        o[2] = (short)f2bf(xa.z); o[3] = (short)f2bf(xa.w);
        o[4] = (short)f2bf(xb4.x); o[5] = (short)f2bf(xb4.y);
        o[6] = (short)f2bf(xb4.z); o[7] = (short)f2bf(xb4.w);
        a[ks] = o;
    }

    f32x4 acc[8];
#pragma unroll
    for (int j = 0; j < 8; ++j) acc[j] = (f32x4){0.f, 0.f, 0.f, 0.f};

    const int sr = tid >> 4;           // 0..15
    const int sc = (tid & 15) * 8;

    for (int kc = 0; kc < 4; ++kc) {
        __syncthreads();
#pragma unroll
        for (int rr = sr; rr < 128; rr += 16)
            *(short8*)&wlds[rr][sc] = *(const short8*)&WtI[rr * IN_DIM + kc * 128 + sc];
        __syncthreads();
#pragma unroll
        for (int ks = 0; ks < 4; ++ks) {
#pragma unroll
            for (int j = 0; j < 8; ++j) {
                short8 bf = *(short8*)&wlds[j * 16 + ln][ks * 32 + grp * 8];
                acc[j] = __builtin_amdgcn_mfma_f32_16x16x32_bf16(a[kc * 4 + ks], bf, acc[j], 0, 0, 0);
            }
        }
    }
    // epilogue: +bias, LN over 128 cols (intra-wave, 16-lane groups), ReLU
    float s1[4] = {0, 0, 0, 0}, s2[4] = {0, 0, 0, 0};
#pragma unroll
    for (int j = 0; j < 8; ++j) {
        float bb = b[j * 16 + ln];
#pragma unroll
        for (int r = 0; r < 4; ++r) {
            float v = acc[j][r] + bb;
            acc[j][r] = v;
            s1[r] += v; s2[r] += v * v;
        }
    }
#pragma unroll
    for (int r = 0; r < 4; ++r) {
#pragma unroll
        for (int off = 8; off; off >>= 1) {
            s1[r] += __shfl_xor(s1[r], off);
            s2[r] += __shfl_xor(s2[r], off);
        }
    }
#pragma unroll
    for (int r = 0; r < 4; ++r) {
        float mu  = s1[r] * (1.f / HID);
        float var = s2[r] * (1.f / HID) - mu * mu;
        float rs  = rsqrtf(var + LN_EPS);
        int row = row0 + grp * 4 + r;
        if (row < N_NODES) {
#pragma unroll
            for (int j = 0; j < 8; ++j) {
                int c = j * 16 + ln;
                float o = (acc[j][r] - mu) * rs * g[c] + beta[c];
                hb[(unsigned)row * HID + c] = f2bf(fmaxf(o, 0.f));
            }
        }
    }
}

// ------- per-layer MFMA: 64-row tile, 256 thr = 4 waves; LDS-staged weights -------
__global__ __launch_bounds__(256) void k_xlxr(
    const unsigned short* __restrict__ hb,
    const unsigned short* __restrict__ Wlt, const unsigned short* __restrict__ Wrt,
    const float* __restrict__ bl, const float* __restrict__ br,
    unsigned short* __restrict__ xlb, unsigned short* __restrict__ xrb)
{
    __shared__ unsigned short wl_lds[128][136];
    __shared__ unsigned short wr_lds[128][136];
    const int tid = threadIdx.x;
    const int wid = tid >> 6;
    const int l   = tid & 63;
    const int grp = l >> 4;
    const int ln  = l & 15;
    const int row0 = blockIdx.x * 64 + wid * 16;
    const int arow = min(row0 + ln, N_NODES - 1);    // clamp for tail block

    const int sr = tid >> 4;           // 0..15
    const int sc = (tid & 15) * 8;
#pragma unroll
    for (int rr = sr; rr < 128; rr += 16) {
        *(short8*)&wl_lds[rr][sc] = *(const short8*)&Wlt[rr * HID + sc];
        *(short8*)&wr_lds[rr][sc] = *(const short8*)&Wrt[rr * HID + sc];
    }

    short8 a[4];
#pragma unroll
    for (int ks = 0; ks < 4; ++ks)
        a[ks] = *(const short8*)&hb[(unsigned)arow * HID + ks * 32 + grp * 8];
    __syncthreads();

    f32x4 aL[8], aR[8];
#pragma unroll
    for (int j = 0; j < 8; ++j) {
        aL[j] = (f32x4){0.f, 0.f, 0.f, 0.f};
        aR[j] = (f32x4){0.f, 0.f, 0.f, 0.f};
    }
#pragma unroll
    for (int ks = 0; ks < 4; ++ks) {
        const int kk = ks * 32 + grp * 8;
#pragma unroll
        for (int j = 0; j < 8; ++j) {
            short8 b8l = *(short8*)&wl_lds[j * 16 + ln][kk];
            aL[j] = __builtin_amdgcn_mfma_f32_16x16x32_bf16(a[ks], b8l, aL[j], 0, 0, 0);
            short8 b8r = *(short8*)&wr_lds[j * 16 + ln][kk];
            aR[j] = __builtin_amdgcn_mfma_f32_16x16x32_bf16(a[ks], b8r, aR[j], 0, 0, 0);
        }
    }
#pragma unroll
    for (int r = 0; r < 4; ++r) {
        int row = row0 + grp * 4 + r;
        if (row < N_NODES) {
#pragma unroll
            for (int j = 0; j < 8; ++j) {
                int c = j * 16 + ln;
                xlb[(unsigned)row * HID + c] = f2bf(aL[j][r] + bl[c]);
                xrb[(unsigned)row * HID + c] = f2bf(aR[j][r] + br[c]);
            }
        }
    }
}

// per-slot work, float2-paired: unpack pairs, logit via packed fma, exp, accumulate
#define PROC(xa, xb_, live) do {                                            \
    f32x2 xf2[8];                                                           \
    _Pragma("unroll")                                                       \
    for (int q = 0; q < 4; ++q) {                                           \
        unsigned w0 = ((const unsigned*)&(xa))[q];                          \
        f32x2 v0;                                                           \
        v0.x = __uint_as_float(w0 << 16);                                   \
        v0.y = __uint_as_float(w0 & 0xffff0000u);                           \
        xf2[q] = v0;                                                        \
        unsigned w1 = ((const unsigned*)&(xb_))[q];                         \
        f32x2 v1;                                                           \
        v1.x = __uint_as_float(w1 << 16);                                   \
        v1.y = __uint_as_float(w1 & 0xffff0000u);                           \
        xf2[4 + q] = v1;                                                    \
    }                                                                       \
    f32x2 ll2 = {0.f, 0.f};                                                 \
    _Pragma("unroll")                                                       \
    for (int q = 0; q < 8; ++q) {                                           \
        f32x2 u = xf2[q] + rv2[q];                                          \
        f32x2 un = u * nsl2;                                                \
        u.x = fmaxf(u.x, un.x);                                             \
        u.y = fmaxf(u.y, un.y);                                             \
        ll2 = u * av2[q] + ll2;                                             \
    }                                                                       \
    float p = (live) ? __expf(ll2.x + ll2.y) : 0.f;                         \
    sp += p;                                                                \
    f32x2 p2 = {p, p};                                                      \
    _Pragma("unroll")                                                       \
    for (int q = 0; q < 8; ++q) acc2[q] = p2 * xf2[q] + acc2[q];            \
} while (0)

// ------- fused GAT layer (R18 champion): ONE WAVE PER NODE, zero barriers, packed-f32 -------
__global__ __launch_bounds__(256) void k_gat(
    const unsigned short* __restrict__ xlb, const unsigned short* __restrict__ xrb,
    const int* __restrict__ adj, const int* __restrict__ cntp,
    const float* __restrict__ att, const float* __restrict__ gbias,
    const float* __restrict__ g, const float* __restrict__ beta,
    const unsigned short* __restrict__ hbin, float* __restrict__ hout,
    unsigned short* __restrict__ hbout)
{
    __shared__ float red[4][136];        // per-wave: [0..127] acc, [128..135] head sums
    const int tid  = threadIdx.x;
    const int wv   = tid >> 6;
    const int lane = tid & 63;
    const int d    = blockIdx.x * 4 + wv;
    const int e    = lane >> 3;
    const int hh   = lane & 7;
    const int cb   = hh * 16;
    const unsigned dC = (unsigned)d * CAP;

    const int nj = min(cntp[d << 4], CAP);   // includes self loop (atomic insert)
    int aj0 = adj[dC + e];               // slots 0..7
    int aj1 = adj[dC + 8 + e];           // slots 8..15
    int aj2 = adj[dC + 16 + e];          // slots 16..23

    const f32x2 nsl2 = {NEG_SLOPE, NEG_SLOPE};
    f32x2 av2[8], rv2[8];
#pragma unroll
    for (int q = 0; q < 8; ++q)
        av2[q] = *(const f32x2*)&att[cb + q * 2];
    {
        const short8* pr = (const short8*)&xrb[(unsigned)d * HID + cb];
        short8 r0 = pr[0], r1 = pr[1];
#pragma unroll
        for (int q = 0; q < 4; ++q) {
            unsigned w0 = ((const unsigned*)&r0)[q];
            f32x2 v0;
            v0.x = __uint_as_float(w0 << 16);
            v0.y = __uint_as_float(w0 & 0xffff0000u);
            rv2[q] = v0;
            unsigned w1 = ((const unsigned*)&r1)[q];
            f32x2 v1;
            v1.x = __uint_as_float(w1 << 16);
            v1.y = __uint_as_float(w1 & 0xffff0000u);
            rv2[4 + q] = v1;
        }
    }

    const int src0 = (e < nj)      ? aj0 : d;
    const int src1 = (8 + e < nj)  ? aj1 : d;
    const int src2 = (16 + e < nj) ? aj2 : d;
    const short8* p0 = (const short8*)&xlb[(unsigned)src0 * HID + cb];
    short8 ga0 = p0[0], gb0 = p0[1];
    const short8* p1 = (const short8*)&xlb[(unsigned)src1 * HID + cb];
    short8 ga1 = p1[0], gb1 = p1[1];

    f32x2 acc2[8];
#pragma unroll
    for (int q = 0; q < 8; ++q) acc2[q] = (f32x2){0.f, 0.f};
    float sp = 0.f;

    if (nj > 16) {                       // wave-uniform branch (~53%)
        const short8* p2 = (const short8*)&xlb[(unsigned)src2 * HID + cb];
        short8 ga2 = p2[0], gb2 = p2[1];
        PROC(ga0, gb0, e < nj);
        PROC(ga1, gb1, true);
        PROC(ga2, gb2, 16 + e < nj);
        for (int ch = 3; (ch << 3) < nj; ++ch) {   // rare: nj > 24 (~3.4%)
            int j = (ch << 3) + e;
            int ajv = adj[dC + (j < nj ? j : 0)];
            int sj  = (j < nj) ? ajv : d;
            const short8* pj = (const short8*)&xlb[(unsigned)sj * HID + cb];
            short8 gaj = pj[0], gbj = pj[1];
            PROC(gaj, gbj, j < nj);
        }
    } else {
        PROC(ga0, gb0, e < nj);
        PROC(ga1, gb1, 8 + e < nj);
    }

    // butterfly reduce across the 8 slot-lanes (e-bits are lane bits 3..5)
#pragma unroll
    for (int m = 8; m < 64; m <<= 1) {
#pragma unroll
        for (int q = 0; q < 8; ++q) {
            acc2[q].x += __shfl_xor(acc2[q].x, m);
            acc2[q].y += __shfl_xor(acc2[q].y, m);
        }
        sp += __shfl_xor(sp, m);
    }

    // wave-private LDS redistribute (no barrier: same-wave LDS dependency)
    if (lane < 8) {                      // lane == hh, e == 0
#pragma unroll
        for (int i = 0; i < 4; ++i) {
            float4 v;
            v.x = acc2[2 * i].x;     v.y = acc2[2 * i].y;
            v.z = acc2[2 * i + 1].x; v.w = acc2[2 * i + 1].y;
            *(float4*)&red[wv][lane * 16 + i * 4] = v;
        }
        red[wv][128 + lane] = sp;
    }
    const int c0 = lane * 2;
    float a0  = red[wv][c0];
    float a1  = red[wv][c0 + 1];
    float ssv = red[wv][128 + e];        // head of channel c0 is c0>>4 == e

    float2 gbv = *(const float2*)&gbias[c0];
    float2 ggv = *(const float2*)&g[c0];
    float2 bev = *(const float2*)&beta[c0];
    unsigned hr2 = *(const unsigned*)&hbin[(unsigned)d * HID + c0];

    float o0 = a0 / ssv + gbv.x;
    float o1 = a1 / ssv + gbv.y;
    o0 = o0 > 0.f ? o0 : (__expf(o0) - 1.f);   // ELU(alpha=1)
    o1 = o1 > 0.f ? o1 : (__expf(o1) - 1.f);
    o0 += bf2f((unsigned short)(hr2 & 0xffffu));
    o1 += bf2f((unsigned short)(hr2 >> 16));

    float s1l = o0 + o1, s2l = o0 * o0 + o1 * o1;
#pragma unroll
    for (int m = 1; m < 64; m <<= 1) {
        s1l += __shfl_xor(s1l, m);
        s2l += __shfl_xor(s2l, m);
    }
    float mu  = s1l * (1.f / HID);
    float var = s2l * (1.f / HID) - mu * mu;
    float rs  = rsqrtf(var + LN_EPS);
    float out0 = (o0 - mu) * rs * ggv.x + bev.x;
    float out1 = (o1 - mu) * rs * ggv.y + bev.y;
    if (hout) {
        float2 ov; ov.x = out0; ov.y = out1;
        *(float2*)&hout[(unsigned)d * HID + c0] = ov;
    }
    if (hbout) {
        unsigned pk = (unsigned)f2bf(out0) | ((unsigned)f2bf(out1) << 16);
        *(unsigned*)&hbout[(unsigned)d * HID + c0] = pk;
    }
}

extern "C" void kernel_launch(void* const* d_in, const int* in_sizes, int n_in,
                              void* d_out, int out_size, void* d_ws, size_t ws_size,
                              hipStream_t stream) {
    (void)in_sizes; (void)n_in; (void)out_size; (void)ws_size;
    const float* x        = (const float*)d_in[0];
    const int*   ei       = (const int*)  d_in[1];
    const float* W_in     = (const float*)d_in[2];
    const float* b_in     = (const float*)d_in[3];
    const float* ln_g     = (const float*)d_in[4];
    const float* ln_b     = (const float*)d_in[5];
    const float* Wl       = (const float*)d_in[6];
    const float* bl       = (const float*)d_in[7];
    const float* Wr       = (const float*)d_in[8];
    const float* br       = (const float*)d_in[9];
    const float* att      = (const float*)d_in[10];
    const float* gat_bias = (const float*)d_in[11];
    const float* norm_g   = (const float*)d_in[12];
    const float* norm_b   = (const float*)d_in[13];
    float* out_f = (float*)d_out;

    char* w = (char*)d_ws;
    int*   adj  = (int*)w;                          w += (size_t)N_NODES * CAP * 4;
    int*   cntp = (int*)w;                          w += (size_t)N_NODES * 64;   // 64B/counter
    unsigned short* hb  = (unsigned short*)w;       w += (size_t)N_NODES * HID * 2;
    unsigned short* xlb = (unsigned short*)w;       w += (size_t)N_NODES * HID * 2;
    unsigned short* xrb = (unsigned short*)w;       w += (size_t)N_NODES * HID * 2;
    unsigned short* WtI = (unsigned short*)w;       w += (size_t)IN_DIM * HID * 2;
    unsigned short* Wlt = (unsigned short*)w;       w += (size_t)LAYERS * HID * HID * 2;
    unsigned short* Wrt = (unsigned short*)w;

    k_convert<<<512, 256, 0, stream>>>(W_in, Wl, Wr, WtI, Wlt, Wrt, cntp);
    k_fused0<<<PROJ_BLKS + EDGE_BLKS + SELF_BLKS, 256, 0, stream>>>(
        x, WtI, b_in, ln_g, ln_b, hb, ei, cntp, adj);

    for (int L = 0; L < LAYERS; ++L) {
        k_xlxr<<<GEMM_BLKS, 256, 0, stream>>>(
            hb, Wlt + (size_t)L * HID * HID, Wrt + (size_t)L * HID * HID,
            bl + (size_t)L * HID, br + (size_t)L * HID, xlb, xrb);
        float*          hout   = (L == LAYERS - 1) ? out_f : (float*)nullptr;
        unsigned short* hbnext = (L == LAYERS - 1) ? (unsigned short*)nullptr : hb;
        k_gat<<<N_NODES / 4, 256, 0, stream>>>(
            xlb, xrb, adj, cntp,
            att + (size_t)L * HEADS * C_DIM, gat_bias + (size_t)L * HID,
            norm_g + (size_t)L * HID, norm_b + (size_t)L * HID, hb, hout, hbnext);
    }
}